// Round 1
// baseline (1792.227 us; speedup 1.0000x reference)
//
#include <hip/hip_runtime.h>

typedef unsigned short u16;
typedef unsigned int u32;
typedef __attribute__((ext_vector_type(8))) short bf16x8;
typedef __attribute__((ext_vector_type(4))) float f32x4;
typedef __attribute__((ext_vector_type(8))) u16 u16x8;

__device__ __forceinline__ u16 f2b(float f) {
  u32 u = __builtin_bit_cast(u32, f);
  u += 0x7fffu + ((u >> 16) & 1u);
  return (u16)(u >> 16);
}
__device__ __forceinline__ float b2f(u16 h) {
  u32 u = ((u32)h) << 16;
  return __builtin_bit_cast(float, u);
}
__device__ __forceinline__ f32x4 mfma16(bf16x8 a, bf16x8 b, f32x4 c) {
  return __builtin_amdgcn_mfma_f32_16x16x32_bf16(a, b, c, 0, 0, 0);
}

// ---------- cast W f32 [4][1024][1024] -> bf16 copy + per-layer transposed copy
__global__ __launch_bounds__(256) void cast_w_kernel(const float* __restrict__ W,
                                                     u16* __restrict__ Wb,
                                                     u16* __restrict__ WbT) {
  __shared__ u16 tile[64][65];
  int L = blockIdx.z, R0 = blockIdx.y * 64, C0 = blockIdx.x * 64;
  const float* Wl = W + (size_t)L * (1024 * 1024);
  u16* Wbl = Wb + (size_t)L * (1024 * 1024);
  u16* WbTl = WbT + (size_t)L * (1024 * 1024);
  int tr = threadIdx.x >> 6, tc = threadIdx.x & 63;
  for (int i = 0; i < 16; ++i) {
    int r = tr * 16 + i;
    u16 v = f2b(Wl[(size_t)(R0 + r) * 1024 + C0 + tc]);
    Wbl[(size_t)(R0 + r) * 1024 + C0 + tc] = v;
    tile[r][tc] = v;
  }
  __syncthreads();
  for (int i = 0; i < 16; ++i) {
    int r = tr * 16 + i;
    WbTl[(size_t)(C0 + r) * 1024 + R0 + tc] = tile[tc][r];
  }
}

// ---------- generic f32 -> bf16 cast (n multiple of 8)
__global__ __launch_bounds__(256) void cast_f32_bf16_kernel(const float* __restrict__ in,
                                                            u16* __restrict__ out, long n8) {
  long i = (long)blockIdx.x * 256 + threadIdx.x;
  long stride = (long)gridDim.x * 256;
  for (; i < n8; i += stride) {
    const float* s = in + i * 8;
    u16x8 o;
#pragma unroll
    for (int j = 0; j < 8; ++j) o[j] = f2b(s[j]);
    *(u16x8*)(out + i * 8) = o;
  }
}

// ---------- embedding gather -> e_bf [4096(=t*4+b)][512]
__global__ __launch_bounds__(256) void gather_e_kernel(const int* __restrict__ ids,
                                                       const float* __restrict__ embed,
                                                       u16* __restrict__ ebf) {
  int row = blockIdx.x * 4 + (threadIdx.x >> 6);
  int lane = threadIdx.x & 63;
  int t = row >> 2, b = row & 3;
  int id = ids[b * 1024 + t];
  const float* src = embed + (size_t)id * 512 + lane * 8;
  u16x8 o;
#pragma unroll
  for (int j = 0; j < 8; ++j) o[j] = f2b(src[j]);
  *(u16x8*)(ebf + (size_t)row * 512 + lane * 8) = o;
}

// ---------- Sall slot 0 = S_{-1} = concat(starter) broadcast over batch
__global__ __launch_bounds__(256) void init_s0_kernel(const float* __restrict__ starter,
                                                      u16* __restrict__ Sall) {
  int i = blockIdx.x * 256 + threadIdx.x;
  if (i < 2048) {
    u16 v = f2b(starter[i]);
    for (int b = 0; b < 4; ++b) Sall[(size_t)b * 2048 + i] = v;
  }
}

// ---------- copy D_i blocks into M/MT diagonals, B3 -> R block3, C0 -> U block0
__global__ __launch_bounds__(256) void assemble_kernel(const u16* __restrict__ Wb,
                                                       const u16* __restrict__ WbT,
                                                       u16* __restrict__ M, u16* __restrict__ MT,
                                                       u16* __restrict__ Rm, u16* __restrict__ Um) {
  int task = blockIdx.y;
  int e = blockIdx.x * 256 + threadIdx.x;  // 0..262143
  int r = e >> 9, c = e & 511;
  if (task < 4) {
    int i = task;
    u16 v = Wb[(size_t)i * 1048576 + (size_t)(512 + r) * 1024 + 512 + c];
    u16 vt = WbT[(size_t)i * 1048576 + (size_t)(512 + r) * 1024 + 512 + c];
    M[(size_t)(i * 512 + r) * 2048 + i * 512 + c] = v;
    MT[(size_t)(i * 512 + r) * 2048 + i * 512 + c] = vt;
  } else if (task == 4) {
    Rm[(size_t)r * 2048 + 3 * 512 + c] = Wb[(size_t)3 * 1048576 + (size_t)r * 1024 + 512 + c];
  } else {
    Um[(size_t)r * 512 + c] = Wb[(size_t)(512 + r) * 1024 + c];
  }
}

// ---------- bias chain: hnew = A_l h + bx_l ; k_l = C_l h + bs_l   (f32, tiny)
__global__ __launch_bounds__(256) void bias_step_kernel(const float* __restrict__ W,
                                                        const float* __restrict__ bv, int layer,
                                                        const float* __restrict__ hin,
                                                        float* __restrict__ hout,
                                                        float* __restrict__ kvec) {
  int wid = threadIdx.x >> 6, lane = threadIdx.x & 63;
  int gw = blockIdx.x * 4 + wid;
  for (int o = gw; o < 1024; o += 64) {
    const float* row = W + (size_t)layer * 1048576 + (size_t)o * 1024;
    float s = 0.f;
    for (int k = lane; k < 512; k += 64) s += row[k] * hin[k];
    for (int off = 32; off; off >>= 1) s += __shfl_down(s, off);
    if (lane == 0) {
      float v = s + bv[layer * 1024 + o];
      if (o < 512) hout[o] = v;
      else kvec[layer * 512 + (o - 512)] = v;
    }
  }
}

// ---------- batched 512x512x512 composer: Out[r,n] = sum_k A[r,k]*B[n,k], optional transposed copy
struct G512 { const u16* A; const u16* B; u16* C; u16* CT; int lda, ldb, ldc, ldt; };
struct G512Args { G512 g[8]; };

__global__ __launch_bounds__(256) void gemm512_kernel(G512Args args) {
  G512 d = args.g[blockIdx.z];
  int wid = threadIdx.x >> 6, lane = threadIdx.x & 63;
  int wr = wid >> 1, wc = wid & 1;
  int row0 = blockIdx.y * 64 + wr * 32, col0 = blockIdx.x * 64 + wc * 32;
  int fr = lane & 15, fk = (lane >> 4) * 8;
  f32x4 acc[2][2] = {};
  for (int kk = 0; kk < 512; kk += 32) {
    bf16x8 a[2], b[2];
#pragma unroll
    for (int m = 0; m < 2; ++m)
      a[m] = *(const bf16x8*)(d.A + (size_t)(row0 + m * 16 + fr) * d.lda + kk + fk);
#pragma unroll
    for (int n = 0; n < 2; ++n)
      b[n] = *(const bf16x8*)(d.B + (size_t)(col0 + n * 16 + fr) * d.ldb + kk + fk);
#pragma unroll
    for (int m = 0; m < 2; ++m)
#pragma unroll
      for (int n = 0; n < 2; ++n) acc[m][n] = mfma16(a[m], b[n], acc[m][n]);
  }
  int dr = (lane >> 4) * 4, dc = lane & 15;
  for (int m = 0; m < 2; ++m)
    for (int n = 0; n < 2; ++n)
#pragma unroll
      for (int j = 0; j < 4; ++j) {
        int r = row0 + m * 16 + dr + j, c = col0 + n * 16 + dc;
        u16 v = f2b(acc[m][n][j]);
        d.C[(size_t)r * d.ldc + c] = v;
        if (d.CT) d.CT[(size_t)c * d.ldt + r] = v;
      }
}

// ---------- main tiled GEMM: Out[r,n] = sum_k A[r,k]*B[n,k] (+bias[n]) (+prev[r,n])
// 128x128 tile, BK=64, LDS-staged, 4 waves each 64x64 quadrant.
template <bool OUT_BF16, bool WRITE_T, bool PERM, bool ADD_PREV, bool HAS_BIAS>
__global__ __launch_bounds__(256) void gemm128_kernel(
    const u16* __restrict__ A, int lda, const u16* __restrict__ B, int ldb, int K,
    void* __restrict__ C, int ldc, u16* __restrict__ CT, int ldt,
    const float* __restrict__ bias, const float* __restrict__ prev, int ldp) {
  __shared__ u16 As[128 * 64];
  __shared__ u16 Bs[128 * 64];
  int tid = threadIdx.x;
  int wid = tid >> 6, lane = tid & 63;
  int wr = wid >> 1, wc = wid & 1;
  int fr = lane & 15, fkb = (lane >> 4) * 8;
  int rowt = blockIdx.y * 128, colt = blockIdx.x * 128;
  f32x4 acc[4][4] = {};
  for (int kk = 0; kk < K; kk += 64) {
#pragma unroll
    for (int i = 0; i < 4; ++i) {
      int q = i * 256 + tid;
      int r = q >> 3, kc = (q & 7) * 8;
      *(bf16x8*)&As[r * 64 + kc] = *(const bf16x8*)(A + (size_t)(rowt + r) * lda + kk + kc);
      *(bf16x8*)&Bs[r * 64 + kc] = *(const bf16x8*)(B + (size_t)(colt + r) * ldb + kk + kc);
    }
    __syncthreads();
#pragma unroll
    for (int kh = 0; kh < 64; kh += 32) {
      bf16x8 a[4], b[4];
#pragma unroll
      for (int m = 0; m < 4; ++m) a[m] = *(const bf16x8*)&As[(wr * 64 + m * 16 + fr) * 64 + kh + fkb];
#pragma unroll
      for (int n = 0; n < 4; ++n) b[n] = *(const bf16x8*)&Bs[(wc * 64 + n * 16 + fr) * 64 + kh + fkb];
#pragma unroll
      for (int m = 0; m < 4; ++m)
#pragma unroll
        for (int n = 0; n < 4; ++n) acc[m][n] = mfma16(a[m], b[n], acc[m][n]);
    }
    __syncthreads();
  }
  int dr = (lane >> 4) * 4, dc = lane & 15;
  for (int m = 0; m < 4; ++m)
    for (int n = 0; n < 4; ++n) {
      int c = colt + wc * 64 + n * 16 + dc;
      float bvv = HAS_BIAS ? bias[c] : 0.f;
#pragma unroll
      for (int j = 0; j < 4; ++j) {
        int r = rowt + wr * 64 + m * 16 + dr + j;
        float v = acc[m][n][j] + bvv;
        if (ADD_PREV) v += prev[(size_t)r * ldp + c];
        int orow = PERM ? ((r & 3) * 1024 + (r >> 2)) : r;
        if (OUT_BF16) ((u16*)C)[(size_t)orow * ldc + c] = f2b(v);
        else ((float*)C)[(size_t)orow * ldc + c] = v;
        if (WRITE_T) CT[(size_t)c * ldt + r] = f2b(v);
      }
    }
}

// ---------- scan step: Out = S@M^T + V over chunked row layout.
// Row r (global 0..nch*4-1): chunk c=r>>2, batch b=r&3; element offset = c*cs + b*2048 + col.
// 32x64-grid of 32-row x 32-col tiles; 4 waves split K (each 512) then LDS-reduce.
__global__ __launch_bounds__(256) void scan_step_kernel(
    const u16* __restrict__ Abase, size_t acs, const u16* __restrict__ M,
    const u16* __restrict__ Vbase, size_t vcs, u16* __restrict__ Obase, size_t ocs, int nch) {
  __shared__ float red[4 * 32 * 32];
  int tid = threadIdx.x, wid = tid >> 6, lane = tid & 63;
  int rt = blockIdx.y * 32, ct = blockIdx.x * 32;
  int fr = lane & 15, fk = (lane >> 4) * 8;
  int kw = wid * 512;
  f32x4 acc[2][2] = {};
  const u16* arow[2];
#pragma unroll
  for (int m = 0; m < 2; ++m) {
    int r = rt + m * 16 + fr;
    int cc = r >> 2;
    if (cc >= nch) cc = nch - 1;
    arow[m] = Abase + (size_t)cc * acs + (size_t)(r & 3) * 2048;
  }
  for (int kk = 0; kk < 512; kk += 32) {
    int k = kw + kk + fk;
    bf16x8 a[2], b[2];
#pragma unroll
    for (int m = 0; m < 2; ++m) a[m] = *(const bf16x8*)(arow[m] + k);
#pragma unroll
    for (int n = 0; n < 2; ++n) b[n] = *(const bf16x8*)(M + (size_t)(ct + n * 16 + fr) * 2048 + k);
#pragma unroll
    for (int m = 0; m < 2; ++m)
#pragma unroll
      for (int n = 0; n < 2; ++n) acc[m][n] = mfma16(a[m], b[n], acc[m][n]);
  }
  int dr = (lane >> 4) * 4, dc = lane & 15;
#pragma unroll
  for (int m = 0; m < 2; ++m)
#pragma unroll
    for (int n = 0; n < 2; ++n)
#pragma unroll
      for (int j = 0; j < 4; ++j)
        red[wid * 1024 + (m * 16 + dr + j) * 32 + n * 16 + dc] = acc[m][n][j];
  __syncthreads();
  for (int t = 0; t < 4; ++t) {
    int o = t * 256 + tid;
    int rl = o >> 5, cl = o & 31;
    int r = rt + rl;
    int cc = r >> 2;
    if (cc < nch) {
      float s = red[rl * 32 + cl] + red[1024 + rl * 32 + cl] + red[2048 + rl * 32 + cl] +
                red[3072 + rl * 32 + cl];
      s += b2f(Vbase[(size_t)cc * vcs + (size_t)(r & 3) * 2048 + ct + cl]);
      Obase[(size_t)cc * ocs + (size_t)(r & 3) * 2048 + ct + cl] = f2b(s);
    }
  }
}

// ---------- pass1 j=0: ping[r] = v_{c*32+0}   (S_hat_0 = v_0)
__global__ __launch_bounds__(256) void copy_v0_kernel(const u16* __restrict__ vbuf,
                                                      u16* __restrict__ ping) {
  int r = blockIdx.x;
  int c = r >> 2, b = r & 3;
  const uint4* src = (const uint4*)(vbuf + (size_t)c * 262144 + (size_t)b * 2048);
  uint4* dst = (uint4*)(ping + (size_t)r * 2048);
  dst[threadIdx.x] = src[threadIdx.x];
}

static inline size_t alignup(size_t x) { return (x + 255) & ~(size_t)255; }

extern "C" void kernel_launch(void* const* d_in, const int* in_sizes, int n_in,
                              void* d_out, int out_size, void* d_ws, size_t ws_size,
                              hipStream_t stream) {
  const int* ids = (const int*)d_in[0];
  const float* embed = (const float*)d_in[1];
  const float* starter = (const float*)d_in[2];
  const float* W = (const float*)d_in[3];
  const float* bvec = (const float*)d_in[4];
  const float* Wout = (const float*)d_in[5];
  const float* bout = (const float*)d_in[6];
  float* out = (float*)d_out;

  char* p = (char*)d_ws;
  auto alloc = [&](size_t bytes) { char* q = p; p += alignup(bytes); return q; };
  u16* Wbf = (u16*)alloc(8388608);
  u16* WbT = (u16*)alloc(8388608);
  u16* Mm = (u16*)alloc(8388608);
  u16* MTm = (u16*)alloc(8388608);
  u16* SQ0 = (u16*)alloc(8388608);
  u16* SQ1 = (u16*)alloc(8388608);
  u16* SQ2 = (u16*)alloc(8388608);
  u16* SQ3 = (u16*)alloc(8388608);
  u16* X2 = (u16*)alloc(524288);  u16* X2T = (u16*)alloc(524288);
  u16* X3 = (u16*)alloc(524288);  u16* X3T = (u16*)alloc(524288);
  u16* P1 = (u16*)alloc(524288);  u16* P1T = (u16*)alloc(524288);
  u16* P2 = (u16*)alloc(524288);  u16* P2T = (u16*)alloc(524288);
  u16* P3 = (u16*)alloc(524288);  u16* P3T = (u16*)alloc(524288);
  u16* Um = (u16*)alloc(2097152);
  u16* Rm = (u16*)alloc(2097152);
  u16* Qm = (u16*)alloc(524288);
  u16* ebf = (u16*)alloc(4194304);
  u16* vbuf = (u16*)alloc(16777216);
  u16* Sall = (u16*)alloc(16777216);
  u16* ping0 = (u16*)alloc(524288);
  u16* ping1 = (u16*)alloc(524288);
  float* yacc = (float*)alloc(8388608);
  u16* ybf = (u16*)alloc(4194304);
  u16* WoutB = (u16*)alloc(32768000);
  float* kvec = (float*)alloc(8192);
  float* h0 = (float*)alloc(2048);
  float* h1 = (float*)alloc(2048);
  if ((size_t)(p - (char*)d_ws) > ws_size) return;  // workspace too small -> loud failure

  // zero M/MT (adjacent) and h0
  hipMemsetAsync(Mm, 0, 16777216, stream);
  hipMemsetAsync(h0, 0, 2048, stream);

  cast_w_kernel<<<dim3(16, 16, 4), 256, 0, stream>>>(W, Wbf, WbT);
  cast_f32_bf16_kernel<<<4096, 256, 0, stream>>>(Wout, WoutB, 32000L * 512 / 8);
  gather_e_kernel<<<1024, 256, 0, stream>>>(ids, embed, ebf);
  init_s0_kernel<<<8, 256, 0, stream>>>(starter, Sall);
  assemble_kernel<<<dim3(1024, 6), 256, 0, stream>>>(Wbf, WbT, Mm, MTm, Rm, Um);

  {  // bias chain (b is zero in this data, but compute generally)
    const float* hin = h0;
    float* hout = h1;
    for (int l = 0; l < 4; ++l) {
      bias_step_kernel<<<16, 256, 0, stream>>>(W, bvec, l, hin, hout, kvec);
      float* t = (float*)hin; hin = hout; hout = t;
    }
  }
  const float* cvec = h0;  // h after layer 3

  auto wb = [&](int i) { return Wbf + (size_t)i * 1048576; };
  auto wbt = [&](int i) { return WbT + (size_t)i * 1048576; };
  const size_t Apos = 0, Cpos = (size_t)512 * 1024;
  auto mblk = [&](int i, int j) { return Mm + (size_t)(i * 512) * 2048 + j * 512; };
  auto mtblk = [&](int i, int j) { return MTm + (size_t)(j * 512) * 2048 + i * 512; };

  {  // level A
    G512Args a{};
    int n = 0;
    auto add = [&](const u16* A_, int lda, const u16* B_, int ldb, u16* C_, int ldc, u16* CT_, int ldt) {
      a.g[n++] = G512{A_, B_, C_, CT_, lda, ldb, ldc, ldt};
    };
    add(wb(1) + Apos, 1024, wbt(0) + Apos, 1024, X2, 512, X2T, 512);          // X2 = A1*A0
    add(wb(1) + Apos, 1024, wbt(0) + Cpos, 1024, P1, 512, P1T, 512);          // P1 = A1*B0
    add(wb(2) + Apos, 1024, wbt(1) + Cpos, 1024, P3, 512, P3T, 512);          // P3 = A2*B1
    add(wb(1) + Cpos, 1024, wbt(0) + Cpos, 1024, mblk(1, 0), 2048, mtblk(1, 0), 2048);  // M10=C1*B0
    add(wb(2) + Cpos, 1024, wbt(1) + Cpos, 1024, mblk(2, 1), 2048, mtblk(2, 1), 2048);  // M21=C2*B1
    add(wb(3) + Apos, 1024, wbt(2) + Cpos, 1024, Rm + 2 * 512, 2048, nullptr, 0);       // R2=A3*B2
    add(wb(3) + Cpos, 1024, wbt(2) + Cpos, 1024, mblk(3, 2), 2048, mtblk(3, 2), 2048);  // M32=C3*B2
    add(wb(1) + Cpos, 1024, wbt(0) + Apos, 1024, Um + (size_t)1 * 262144, 512, nullptr, 0);  // U1=C1*A0
    gemm512_kernel<<<dim3(8, 8, 8), 256, 0, stream>>>(a);
  }
  {  // level B
    G512Args a{};
    int n = 0;
    auto add = [&](const u16* A_, int lda, const u16* B_, int ldb, u16* C_, int ldc, u16* CT_, int ldt) {
      a.g[n++] = G512{A_, B_, C_, CT_, lda, ldb, ldc, ldt};
    };
    add(wb(2) + Apos, 1024, X2T, 512, X3, 512, X3T, 512);                     // X3 = A2*X2
    add(wb(2) + Apos, 1024, P1T, 512, P2, 512, P2T, 512);                     // P2 = A2*P1
    add(wb(2) + Cpos, 1024, P1T, 512, mblk(2, 0), 2048, mtblk(2, 0), 2048);   // M20=C2*P1
    add(wb(3) + Apos, 1024, P3T, 512, Rm + 512, 2048, nullptr, 0);            // R1=A3*P3
    add(wb(3) + Cpos, 1024, P3T, 512, mblk(3, 1), 2048, mtblk(3, 1), 2048);   // M31=C3*P3
    add(wb(2) + Cpos, 1024, X2T, 512, Um + (size_t)2 * 262144, 512, nullptr, 0);  // U2=C2*X2
    gemm512_kernel<<<dim3(8, 8, 6), 256, 0, stream>>>(a);
  }
  {  // level C
    G512Args a{};
    int n = 0;
    auto add = [&](const u16* A_, int lda, const u16* B_, int ldb, u16* C_, int ldc, u16* CT_, int ldt) {
      a.g[n++] = G512{A_, B_, C_, CT_, lda, ldb, ldc, ldt};
    };
    add(wb(3) + Apos, 1024, X3T, 512, Qm, 512, nullptr, 0);                   // Q = A3*X3
    add(wb(3) + Apos, 1024, P2T, 512, Rm, 2048, nullptr, 0);                  // R0=A3*P2
    add(wb(3) + Cpos, 1024, P2T, 512, mblk(3, 0), 2048, mtblk(3, 0), 2048);   // M30=C3*P2
    add(wb(3) + Cpos, 1024, X3T, 512, Um + (size_t)3 * 262144, 512, nullptr, 0);  // U3=C3*X3
    gemm512_kernel<<<dim3(8, 8, 4), 256, 0, stream>>>(a);
  }

  // M^32 via 5 squarings (keeps transposed copy for next squaring)
  u16* cur = Mm;
  u16* curT = MTm;
  for (int s = 0; s < 5; ++s) {
    u16* nx = (s & 1) ? SQ2 : SQ0;
    u16* nxT = (s & 1) ? SQ3 : SQ1;
    gemm128_kernel<true, true, false, false, false><<<dim3(16, 16), 256, 0, stream>>>(
        cur, 2048, curT, 2048, 2048, (void*)nx, 2048, nxT, 2048, nullptr, nullptr, 0);
    cur = nx; curT = nxT;
  }
  u16* M32 = cur;  // SQ0

  // v = e @ U^T + k   [4096, 2048] bf16
  gemm128_kernel<true, false, false, false, true><<<dim3(16, 32), 256, 0, stream>>>(
      ebf, 512, Um, 512, 512, (void*)vbuf, 2048, nullptr, 0, kvec, nullptr, 0);

  // ---- pass 1: per-chunk from zero state; 31 steps; result ping = w_c stack
  copy_v0_kernel<<<128, 256, 0, stream>>>(vbuf, ping0);
  u16* pg[2] = {ping0, ping1};
  int pc = 0;
  for (int j = 1; j < 32; ++j) {
    scan_step_kernel<<<dim3(64, 4), 256, 0, stream>>>(
        pg[pc], 8192, Mm, vbuf + (size_t)j * 8192, 262144, pg[pc ^ 1], 8192, 32);
    pc ^= 1;
  }
  u16* wstack = pg[pc];

  // ---- pass 2: chunk boundary states: Sall[32(c+1)] = M^32 * Sall[32c] + w_c
  for (int c = 0; c < 31; ++c) {
    scan_step_kernel<<<dim3(64, 1), 256, 0, stream>>>(
        Sall + (size_t)c * 262144, 0, M32, wstack + (size_t)c * 8192, 0,
        Sall + (size_t)(c + 1) * 262144, 0, 1);
  }

  // ---- pass 3: fill interior states (j = 0..30); slot t holds S_{t-1}
  for (int j = 0; j < 31; ++j) {
    scan_step_kernel<<<dim3(64, 4), 256, 0, stream>>>(
        Sall + (size_t)j * 8192, 262144, Mm, vbuf + (size_t)j * 8192, 262144,
        Sall + (size_t)(j + 1) * 8192, 262144, 32);
  }

  // y = Sall @ R^T + e @ Q^T + c
  gemm128_kernel<false, false, false, false, false><<<dim3(4, 32), 256, 0, stream>>>(
      Sall, 2048, Rm, 2048, 2048, (void*)yacc, 512, nullptr, 0, nullptr, nullptr, 0);
  gemm128_kernel<true, false, false, true, true><<<dim3(4, 32), 256, 0, stream>>>(
      ebf, 512, Qm, 512, 512, (void*)ybf, 512, nullptr, 0, cvec, yacc, 512);

  // logits = y @ Wout^T + bout, rows permuted (t*4+b) -> (b*1024+t)
  gemm128_kernel<false, false, true, false, true><<<dim3(250, 32), 256, 0, stream>>>(
      ybf, 512, WoutB, 512, 512, (void*)out, 32000, nullptr, 0, bout, nullptr, 0);
}